// Round 1
// baseline (15738.004 us; speedup 1.0000x reference)
//
#include <hip/hip_runtime.h>

typedef short v8s __attribute__((ext_vector_type(8)));
typedef float v4f __attribute__((ext_vector_type(4)));

constexpr int H_ = 1024, B_ = 64, T_ = 512;
constexpr int RPITCH = 17;
constexpr unsigned NBLK = 256;

static __device__ __forceinline__ float bf2f(unsigned short u) {
    unsigned v = ((unsigned)u) << 16;
    return __builtin_bit_cast(float, v);
}
static __device__ __forceinline__ unsigned short f2bf(float f) {
    unsigned u = __builtin_bit_cast(unsigned, f);
    u += 0x7fffu + ((u >> 16) & 1u);
    return (unsigned short)(u >> 16);
}

// ws layout (ushort units):
constexpr size_t WOFF_HHI = 0;                            // [2][B*H] h hi (dbuf)
constexpr size_t WOFF_HLO = 2u * B_ * H_;                 // [2][B*H] h lo
constexpr size_t WOFF_WHI = 4u * B_ * H_;                 // [4][1024][1024] W hi
constexpr size_t WOFF_WLO = WOFF_WHI + 4u * 1024 * 1024;  // [4][1024][1024] W lo
constexpr size_t WOFF_CNT = WOFF_WLO + 4u * 1024 * 1024;  // 1 unsigned barrier counter
// total ~16.5 MB

// stage fp32 weights as bf16 hi/lo pairs (gate order: Wmu, Wgmu, Wga, Wa)
__global__ __launch_bounds__(256)
void conv_w_kernel(const float* __restrict__ Wmu, const float* __restrict__ Wgmu,
                   const float* __restrict__ Wga, const float* __restrict__ Wa,
                   unsigned short* __restrict__ ws)
{
    const float* src[4] = { Wmu, Wgmu, Wga, Wa };
    unsigned idx = blockIdx.x * 256 + threadIdx.x;   // [0, 4M)
    unsigned g = idx >> 20, rem = idx & 0xFFFFFu;
    float v = src[g][rem];
    unsigned short hi = f2bf(v);
    unsigned short lo = f2bf(v - bf2f(hi));
    ws[WOFF_WHI + idx] = hi;
    ws[WOFF_WLO + idx] = lo;
}

__global__ __launch_bounds__(256)
void init_h_kernel(unsigned short* __restrict__ ws)
{
    unsigned gid = blockIdx.x * 256 + threadIdx.x;   // 256 blocks -> 65536
    ws[WOFF_HHI + gid] = 0;
    ws[WOFF_HLO + gid] = 0;
    if (gid == 0) *(unsigned*)(ws + WOFF_CNT) = 0u;  // reset grid barrier
}

__global__ __launch_bounds__(256)
void sentinel_kernel(float* __restrict__ out, float val, int n)
{
    int gid = blockIdx.x * 256 + threadIdx.x;
    if (gid < n) out[gid] = val;
}

// Persistent kernel: all T steps in one launch.
// Grid: 256 blocks = 64 col-groups x 4 row-groups; 256 threads = 4 waves (K split 256).
// Weights live in REGISTERS (64 v8s/lane = B-fragments for this wave's K-slice).
// One device-scope grid barrier per step. Numerics bit-identical to the per-step kernel.
__global__ __launch_bounds__(256, 1)
void plasdyn_persist(const float* __restrict__ xv,
                     const float* __restrict__ Bmu, const float* __restrict__ Bgmu,
                     const float* __restrict__ Bga, const float* __restrict__ Ba,
                     float* __restrict__ out, unsigned short* __restrict__ ws)
{
    __shared__ float red[4 * 4 * 16 * RPITCH];   // [wave][gate][row][RPITCH]

    const int tid = threadIdx.x, bid = blockIdx.x;
    const int colbase = (bid & 63) * 16;
    const int rowbase = (bid >> 6) * 16;
    const int wave = tid >> 6, lane = tid & 63;
    const int m = lane & 15, quad = lane >> 4;
    const int kbase = wave * 256;
    const int rowm = rowbase + m;

    // ---- one-time: stage this wave's weight B-fragments in registers ----
    v8s wh[4][8], wl[4][8];
    #pragma unroll
    for (int g = 0; g < 4; ++g) {
        const unsigned short* ph = ws + WOFF_WHI + ((size_t)(g * 1024 + colbase + m) << 10) + kbase;
        const unsigned short* pl = ws + WOFF_WLO + ((size_t)(g * 1024 + colbase + m) << 10) + kbase;
        #pragma unroll
        for (int s = 0; s < 8; ++s) {
            wh[g][s] = *(const v8s*)(ph + s * 32 + quad * 8);
            wl[g][s] = *(const v8s*)(pl + s * 32 + quad * 8);
        }
    }

    unsigned* cnt = (unsigned*)(ws + WOFF_CNT);

    // combine-phase coords + hoisted biases (loop-invariant)
    const int row = tid >> 4, col = tid & 15;
    const int gcol = colbase + col;
    const int grow = rowbase + row;
    const float bmu = Bmu[gcol], bgmu = Bgmu[gcol], bga = Bga[gcol], ba = Ba[gcol];

    for (int t = 0; t < T_; ++t) {
        const int cur = t & 1, nxt = cur ^ 1;
        const unsigned short* hh = ws + WOFF_HHI + cur * (B_ * H_) + rowm * H_;
        const unsigned short* hl = ws + WOFF_HLO + cur * (B_ * H_) + rowm * H_;
        const float* xr = xv + ((size_t)rowm * T_ + t) * H_;   // batch-major [B,T,H]

        v4f acc0 = {0,0,0,0}, acc1 = {0,0,0,0}, acc2 = {0,0,0,0}, acc3 = {0,0,0,0};

        #pragma unroll
        for (int s = 0; s < 8; ++s) {
            const int k0 = kbase + s * 32 + quad * 8;
            v8s ahi = *(const v8s*)(hh + k0);
            v8s alo = *(const v8s*)(hl + k0);

            // x: fp32 -> bf16 hi/lo on the fly (identical math to baseline)
            float4 f0 = *(const float4*)(xr + k0);
            float4 f1 = *(const float4*)(xr + k0 + 4);
            float fv[8] = { f0.x, f0.y, f0.z, f0.w, f1.x, f1.y, f1.z, f1.w };
            v8s xh, xl;
            #pragma unroll
            for (int j = 0; j < 8; ++j) {
                unsigned short hb = f2bf(fv[j]);
                xh[j] = (short)hb;
                xl[j] = (short)f2bf(fv[j] - bf2f(hb));
            }

            acc0 = __builtin_amdgcn_mfma_f32_16x16x32_bf16(ahi, wh[0][s], acc0, 0, 0, 0);
            acc1 = __builtin_amdgcn_mfma_f32_16x16x32_bf16(ahi, wh[1][s], acc1, 0, 0, 0);
            acc2 = __builtin_amdgcn_mfma_f32_16x16x32_bf16(ahi, wh[2][s], acc2, 0, 0, 0);
            acc3 = __builtin_amdgcn_mfma_f32_16x16x32_bf16(xh,  wh[3][s], acc3, 0, 0, 0);
            acc0 = __builtin_amdgcn_mfma_f32_16x16x32_bf16(alo, wh[0][s], acc0, 0, 0, 0);
            acc1 = __builtin_amdgcn_mfma_f32_16x16x32_bf16(alo, wh[1][s], acc1, 0, 0, 0);
            acc2 = __builtin_amdgcn_mfma_f32_16x16x32_bf16(alo, wh[2][s], acc2, 0, 0, 0);
            acc3 = __builtin_amdgcn_mfma_f32_16x16x32_bf16(xl,  wh[3][s], acc3, 0, 0, 0);
            acc0 = __builtin_amdgcn_mfma_f32_16x16x32_bf16(ahi, wl[0][s], acc0, 0, 0, 0);
            acc1 = __builtin_amdgcn_mfma_f32_16x16x32_bf16(ahi, wl[1][s], acc1, 0, 0, 0);
            acc2 = __builtin_amdgcn_mfma_f32_16x16x32_bf16(ahi, wl[2][s], acc2, 0, 0, 0);
            acc3 = __builtin_amdgcn_mfma_f32_16x16x32_bf16(xh,  wl[3][s], acc3, 0, 0, 0);
        }

        // partials -> LDS  (C/D layout: col=lane&15, row=quad*4+reg)
        {
            float* rw = red + wave * (4 * 16 * RPITCH);
            #pragma unroll
            for (int r = 0; r < 4; ++r) {
                int rr = quad * 4 + r;
                rw[(0 * 16 + rr) * RPITCH + m] = acc0[r];
                rw[(1 * 16 + rr) * RPITCH + m] = acc1[r];
                rw[(2 * 16 + rr) * RPITCH + m] = acc2[r];
                rw[(3 * 16 + rr) * RPITCH + m] = acc3[r];
            }
        }
        __syncthreads();

        // combine: one thread per (row,col) of the 16x16 tile
        {
            float z0 = 0.f, z1 = 0.f, z2 = 0.f, z3 = 0.f;
            #pragma unroll
            for (int w = 0; w < 4; ++w) {
                const float* rr = red + w * (4 * 16 * RPITCH);
                z0 += rr[(0 * 16 + row) * RPITCH + col];
                z1 += rr[(1 * 16 + row) * RPITCH + col];
                z2 += rr[(2 * 16 + row) * RPITCH + col];
                z3 += rr[(3 * 16 + row) * RPITCH + col];
            }
            z0 += bmu; z1 += bgmu; z2 += bga; z3 += ba;
            const float s1 = 1.0f / (1.0f + __expf(-z1));
            const float s2 = 1.0f / (1.0f + __expf(-z2));
            float hval = z0 * s1 + z3 * s2;
            hval = fminf(fmaxf(hval, -64.0f), 64.0f);   // NaN-squash safety

            const unsigned short hi16 = f2bf(hval);
            const unsigned short lo16 = f2bf(hval - bf2f(hi16));
            ws[WOFF_HHI + nxt * (B_ * H_) + grow * H_ + gcol] = hi16;
            ws[WOFF_HLO + nxt * (B_ * H_) + grow * H_ + gcol] = lo16;
            if (t == T_ - 1) out[(size_t)grow * H_ + gcol] = hval;   // FP32 output
        }

        // ---- device-scope grid barrier (skip after last step) ----
        if (t != T_ - 1) {
            __syncthreads();   // all h' stores of this block issued & drained
            if (tid == 0) {
                __threadfence();                         // release: flush L2 to coherence point
                __hip_atomic_fetch_add(cnt, 1u, __ATOMIC_RELEASE, __HIP_MEMORY_SCOPE_AGENT);
                const unsigned target = NBLK * (unsigned)(t + 1);
                while (__hip_atomic_load(cnt, __ATOMIC_RELAXED, __HIP_MEMORY_SCOPE_AGENT) < target) {
                    __builtin_amdgcn_s_sleep(2);
                }
                __threadfence();                         // acquire: invalidate L1/L2
            }
            __syncthreads();
        }
    }
}

extern "C" void kernel_launch(void* const* d_in, const int* in_sizes, int n_in,
                              void* d_out, int out_size, void* d_ws, size_t ws_size,
                              hipStream_t stream)
{
    float* out = (float*)d_out;
    unsigned short* ws = (unsigned short*)d_ws;

    const int SZ_X = B_ * T_ * H_;
    const int SZ_W = H_ * H_;
    const int SZ_B = H_;

    bool dict_pat = (n_in == 9 &&
        in_sizes[0] == SZ_X &&
        in_sizes[1] == SZ_W && in_sizes[3] == SZ_W && in_sizes[5] == SZ_W && in_sizes[7] == SZ_W &&
        in_sizes[2] == SZ_B && in_sizes[4] == SZ_B && in_sizes[6] == SZ_B && in_sizes[8] == SZ_B);

    if (!dict_pat) {
        hipLaunchKernelGGL(sentinel_kernel, dim3((out_size + 255) / 256), dim3(256), 0, stream,
                           out, 2000.0f, out_size);
        return;
    }

    // dict order: x, W_mu, b_mu, Wg_mu, bg_mu, W_a, b_a, Wg_a, bg_a  (all fp32)
    const float* x    = (const float*)d_in[0];
    const float* Wmu  = (const float*)d_in[1];
    const float* bmu  = (const float*)d_in[2];
    const float* Wgmu = (const float*)d_in[3];
    const float* bgmu = (const float*)d_in[4];
    const float* Wa   = (const float*)d_in[5];
    const float* ba   = (const float*)d_in[6];
    const float* Wga  = (const float*)d_in[7];
    const float* bga  = (const float*)d_in[8];

    hipLaunchKernelGGL(conv_w_kernel, dim3(16384), dim3(256), 0, stream,
                       Wmu, Wgmu, Wga, Wa, ws);
    hipLaunchKernelGGL(init_h_kernel, dim3(256), dim3(256), 0, stream, ws);

    // one persistent launch runs all T=512 steps; 256 blocks @ 1 block/CU => all co-resident
    hipLaunchKernelGGL(plasdyn_persist, dim3(256), dim3(256), 0, stream,
                       x, bmu, bgmu, bga, ba, out, ws);
}

// Round 2
// 6583.746 us; speedup vs baseline: 2.3904x; 2.3904x over previous
//
#include <hip/hip_runtime.h>

typedef short v8s __attribute__((ext_vector_type(8)));
typedef float v4f __attribute__((ext_vector_type(4)));

constexpr int H_ = 1024, B_ = 64, T_ = 512;
constexpr int RPITCH = 17;

static __device__ __forceinline__ float bf2f(unsigned short u) {
    unsigned v = ((unsigned)u) << 16;
    return __builtin_bit_cast(float, v);
}
static __device__ __forceinline__ unsigned short f2bf(float f) {
    unsigned u = __builtin_bit_cast(unsigned, f);
    u += 0x7fffu + ((u >> 16) & 1u);
    return (unsigned short)(u >> 16);
}

// ws layout (ushort units):
//   packed h: [2][B*H] u32  (hi<<16 | lo)  -> 2*B*H u32 = 4*B*H ushorts (same as old hi/lo)
constexpr size_t WOFF_HPK = 0;                             // u32 area, 131072 u32
constexpr size_t WOFF_WHI = 4u * B_ * H_;                  // [4][1024][1024] W hi (ushort)
constexpr size_t WOFF_WLO = WOFF_WHI + 4u * 1024 * 1024;   // [4][1024][1024] W lo (ushort)
constexpr size_t WOFF_SYNC = WOFF_WLO + 4u * 1024 * 1024;  // u32 sync area (1024 u32)
// sync u32 indices (each slot padded to its own 128B line):
//   counters: slot i at [i*32], i=0..15 ; root at [16*32] ; go flag at [17*32]

// stage fp32 weights as bf16 hi/lo pairs (gate order: Wmu, Wgmu, Wga, Wa)
__global__ __launch_bounds__(256)
void conv_w_kernel(const float* __restrict__ Wmu, const float* __restrict__ Wgmu,
                   const float* __restrict__ Wga, const float* __restrict__ Wa,
                   unsigned short* __restrict__ ws)
{
    const float* src[4] = { Wmu, Wgmu, Wga, Wa };
    unsigned idx = blockIdx.x * 256 + threadIdx.x;   // [0, 4M)
    unsigned g = idx >> 20, rem = idx & 0xFFFFFu;
    float v = src[g][rem];
    unsigned short hi = f2bf(v);
    unsigned short lo = f2bf(v - bf2f(hi));
    ws[WOFF_WHI + idx] = hi;
    ws[WOFF_WLO + idx] = lo;
}

__global__ __launch_bounds__(256)
void init_h_kernel(unsigned short* __restrict__ ws)
{
    unsigned gid = blockIdx.x * 256 + threadIdx.x;   // 256 blocks -> 65536 threads
    unsigned* hpk = (unsigned*)(ws + WOFF_HPK);
    hpk[gid] = 0u;
    hpk[gid + 65536u] = 0u;
    unsigned* syncp = (unsigned*)(ws + WOFF_SYNC);
    if (gid < 1024u) syncp[gid] = 0u;
}

__global__ __launch_bounds__(256)
void sentinel_kernel(float* __restrict__ out, float val, int n)
{
    int gid = blockIdx.x * 256 + threadIdx.x;
    if (gid < n) out[gid] = val;
}

// Persistent kernel: all T steps in one launch.
// Grid: 256 blocks = 64 col-groups x 4 row-groups; 256 threads = 4 waves (K split 256).
// Weights live in registers (AGPR-eligible). h exchanged via agent-scope relaxed
// atomics on packed u32 (cache-bypassing, coherent at LLC) -> NO threadfence, NO
// L2 invalidation per step. Hierarchical 16-slot barrier + go flag.
__global__ __launch_bounds__(256, 1)
void plasdyn_persist(const float* __restrict__ xv,
                     const float* __restrict__ Bmu, const float* __restrict__ Bgmu,
                     const float* __restrict__ Bga, const float* __restrict__ Ba,
                     float* __restrict__ out, unsigned short* __restrict__ ws)
{
    __shared__ float red[4 * 4 * 16 * RPITCH];   // [wave][gate][row][RPITCH]

    const int tid = threadIdx.x, bid = blockIdx.x;
    const int colbase = (bid & 63) * 16;
    const int rowbase = (bid >> 6) * 16;
    const int wave = tid >> 6, lane = tid & 63;
    const int m = lane & 15, quad = lane >> 4;
    const int kbase = wave * 256;
    const int rowm = rowbase + m;

    unsigned* hpk = (unsigned*)(ws + WOFF_HPK);      // [2][B*H] packed h
    unsigned* syncp = (unsigned*)(ws + WOFF_SYNC);

    // ---- one-time: stage this wave's weight B-fragments in registers ----
    v8s wh[4][8], wl[4][8];
    #pragma unroll
    for (int g = 0; g < 4; ++g) {
        const unsigned short* ph = ws + WOFF_WHI + ((size_t)(g * 1024 + colbase + m) << 10) + kbase;
        const unsigned short* pl = ws + WOFF_WLO + ((size_t)(g * 1024 + colbase + m) << 10) + kbase;
        #pragma unroll
        for (int s = 0; s < 8; ++s) {
            wh[g][s] = *(const v8s*)(ph + s * 32 + quad * 8);
            wl[g][s] = *(const v8s*)(pl + s * 32 + quad * 8);
        }
    }

    // combine-phase coords + hoisted biases (loop-invariant)
    const int row = tid >> 4, col = tid & 15;
    const int gcol = colbase + col;
    const int grow = rowbase + row;
    const float bmu = Bmu[gcol], bgmu = Bgmu[gcol], bga = Bga[gcol], ba = Ba[gcol];

    for (int t = 0; t < T_; ++t) {
        const int cur = t & 1, nxt = cur ^ 1;
        const unsigned* hrow = hpk + cur * (B_ * H_) + rowm * H_;
        const float* xr = xv + ((size_t)rowm * T_ + t) * H_;   // batch-major [B,T,H]

        v4f acc0 = {0,0,0,0}, acc1 = {0,0,0,0}, acc2 = {0,0,0,0}, acc3 = {0,0,0,0};

        #pragma unroll
        for (int s = 0; s < 8; ++s) {
            const int k0 = kbase + s * 32 + quad * 8;

            // h: coherent (agent-scope, cache-bypassing) packed loads
            unsigned hu[8];
            #pragma unroll
            for (int j = 0; j < 8; ++j)
                hu[j] = __hip_atomic_load(hrow + k0 + j, __ATOMIC_RELAXED, __HIP_MEMORY_SCOPE_AGENT);
            v8s ahi, alo;
            #pragma unroll
            for (int j = 0; j < 8; ++j) {
                ahi[j] = (short)(hu[j] >> 16);
                alo[j] = (short)(hu[j] & 0xFFFFu);
            }

            // x: fp32 -> bf16 hi/lo on the fly (identical math to baseline)
            float4 f0 = *(const float4*)(xr + k0);
            float4 f1 = *(const float4*)(xr + k0 + 4);
            float fv[8] = { f0.x, f0.y, f0.z, f0.w, f1.x, f1.y, f1.z, f1.w };
            v8s xh, xl;
            #pragma unroll
            for (int j = 0; j < 8; ++j) {
                unsigned short hb = f2bf(fv[j]);
                xh[j] = (short)hb;
                xl[j] = (short)f2bf(fv[j] - bf2f(hb));
            }

            acc0 = __builtin_amdgcn_mfma_f32_16x16x32_bf16(ahi, wh[0][s], acc0, 0, 0, 0);
            acc1 = __builtin_amdgcn_mfma_f32_16x16x32_bf16(ahi, wh[1][s], acc1, 0, 0, 0);
            acc2 = __builtin_amdgcn_mfma_f32_16x16x32_bf16(ahi, wh[2][s], acc2, 0, 0, 0);
            acc3 = __builtin_amdgcn_mfma_f32_16x16x32_bf16(xh,  wh[3][s], acc3, 0, 0, 0);
            acc0 = __builtin_amdgcn_mfma_f32_16x16x32_bf16(alo, wh[0][s], acc0, 0, 0, 0);
            acc1 = __builtin_amdgcn_mfma_f32_16x16x32_bf16(alo, wh[1][s], acc1, 0, 0, 0);
            acc2 = __builtin_amdgcn_mfma_f32_16x16x32_bf16(alo, wh[2][s], acc2, 0, 0, 0);
            acc3 = __builtin_amdgcn_mfma_f32_16x16x32_bf16(xl,  wh[3][s], acc3, 0, 0, 0);
            acc0 = __builtin_amdgcn_mfma_f32_16x16x32_bf16(ahi, wl[0][s], acc0, 0, 0, 0);
            acc1 = __builtin_amdgcn_mfma_f32_16x16x32_bf16(ahi, wl[1][s], acc1, 0, 0, 0);
            acc2 = __builtin_amdgcn_mfma_f32_16x16x32_bf16(ahi, wl[2][s], acc2, 0, 0, 0);
            acc3 = __builtin_amdgcn_mfma_f32_16x16x32_bf16(xh,  wl[3][s], acc3, 0, 0, 0);
        }

        // partials -> LDS  (C/D layout: col=lane&15, row=quad*4+reg)
        {
            float* rw = red + wave * (4 * 16 * RPITCH);
            #pragma unroll
            for (int r = 0; r < 4; ++r) {
                int rr = quad * 4 + r;
                rw[(0 * 16 + rr) * RPITCH + m] = acc0[r];
                rw[(1 * 16 + rr) * RPITCH + m] = acc1[r];
                rw[(2 * 16 + rr) * RPITCH + m] = acc2[r];
                rw[(3 * 16 + rr) * RPITCH + m] = acc3[r];
            }
        }
        __syncthreads();

        // combine: one thread per (row,col) of the 16x16 tile
        {
            float z0 = 0.f, z1 = 0.f, z2 = 0.f, z3 = 0.f;
            #pragma unroll
            for (int w = 0; w < 4; ++w) {
                const float* rr = red + w * (4 * 16 * RPITCH);
                z0 += rr[(0 * 16 + row) * RPITCH + col];
                z1 += rr[(1 * 16 + row) * RPITCH + col];
                z2 += rr[(2 * 16 + row) * RPITCH + col];
                z3 += rr[(3 * 16 + row) * RPITCH + col];
            }
            z0 += bmu; z1 += bgmu; z2 += bga; z3 += ba;
            const float s1 = 1.0f / (1.0f + __expf(-z1));
            const float s2 = 1.0f / (1.0f + __expf(-z2));
            float hval = z0 * s1 + z3 * s2;
            hval = fminf(fmaxf(hval, -64.0f), 64.0f);   // NaN-squash safety

            const unsigned short hi16 = f2bf(hval);
            const unsigned short lo16 = f2bf(hval - bf2f(hi16));
            const unsigned pk = ((unsigned)hi16 << 16) | (unsigned)lo16;
            __hip_atomic_store(hpk + nxt * (B_ * H_) + grow * H_ + gcol, pk,
                               __ATOMIC_RELAXED, __HIP_MEMORY_SCOPE_AGENT);
            if (t == T_ - 1) out[(size_t)grow * H_ + gcol] = hval;   // FP32 output
        }

        // ---- grid barrier: NO threadfence. __syncthreads drains vmcnt(0), so all
        // h stores (cache-bypassing) are at the coherence point before we signal. ----
        if (t != T_ - 1) {
            __syncthreads();
            if (tid == 0) {
                const unsigned slot = (unsigned)bid & 15u;
                unsigned old = __hip_atomic_fetch_add(&syncp[slot * 32], 1u,
                                                      __ATOMIC_RELAXED, __HIP_MEMORY_SCOPE_AGENT);
                if (old == 16u * (unsigned)(t + 1) - 1u) {
                    unsigned ro = __hip_atomic_fetch_add(&syncp[16 * 32], 1u,
                                                         __ATOMIC_RELAXED, __HIP_MEMORY_SCOPE_AGENT);
                    if (ro == 16u * (unsigned)(t + 1) - 1u)
                        __hip_atomic_store(&syncp[17 * 32], (unsigned)(t + 1),
                                           __ATOMIC_RELAXED, __HIP_MEMORY_SCOPE_AGENT);
                }
                while (__hip_atomic_load(&syncp[17 * 32], __ATOMIC_RELAXED,
                                         __HIP_MEMORY_SCOPE_AGENT) < (unsigned)(t + 1)) {
                    __builtin_amdgcn_s_sleep(1);
                }
            }
            __syncthreads();
        }
    }
}

extern "C" void kernel_launch(void* const* d_in, const int* in_sizes, int n_in,
                              void* d_out, int out_size, void* d_ws, size_t ws_size,
                              hipStream_t stream)
{
    float* out = (float*)d_out;
    unsigned short* ws = (unsigned short*)d_ws;

    const int SZ_X = B_ * T_ * H_;
    const int SZ_W = H_ * H_;
    const int SZ_B = H_;

    bool dict_pat = (n_in == 9 &&
        in_sizes[0] == SZ_X &&
        in_sizes[1] == SZ_W && in_sizes[3] == SZ_W && in_sizes[5] == SZ_W && in_sizes[7] == SZ_W &&
        in_sizes[2] == SZ_B && in_sizes[4] == SZ_B && in_sizes[6] == SZ_B && in_sizes[8] == SZ_B);

    if (!dict_pat) {
        hipLaunchKernelGGL(sentinel_kernel, dim3((out_size + 255) / 256), dim3(256), 0, stream,
                           out, 2000.0f, out_size);
        return;
    }

    // dict order: x, W_mu, b_mu, Wg_mu, bg_mu, W_a, b_a, Wg_a, bg_a  (all fp32)
    const float* x    = (const float*)d_in[0];
    const float* Wmu  = (const float*)d_in[1];
    const float* bmu  = (const float*)d_in[2];
    const float* Wgmu = (const float*)d_in[3];
    const float* bgmu = (const float*)d_in[4];
    const float* Wa   = (const float*)d_in[5];
    const float* ba   = (const float*)d_in[6];
    const float* Wga  = (const float*)d_in[7];
    const float* bga  = (const float*)d_in[8];

    hipLaunchKernelGGL(conv_w_kernel, dim3(16384), dim3(256), 0, stream,
                       Wmu, Wgmu, Wga, Wa, ws);
    hipLaunchKernelGGL(init_h_kernel, dim3(256), dim3(256), 0, stream, ws);

    // one persistent launch runs all T=512 steps; 256 blocks @ 1 block/CU => all co-resident
    hipLaunchKernelGGL(plasdyn_persist, dim3(256), dim3(256), 0, stream,
                       x, bmu, bgmu, bga, ba, out, ws);
}

// Round 3
// 4298.997 us; speedup vs baseline: 3.6609x; 1.5315x over previous
//
#include <hip/hip_runtime.h>

typedef short v8s __attribute__((ext_vector_type(8)));
typedef float v4f __attribute__((ext_vector_type(4)));

constexpr int H_ = 1024, B_ = 64, T_ = 512;
constexpr int RPITCH = 17;
constexpr int BH = B_ * H_;   // u32 elements per h buffer

static __device__ __forceinline__ float bf2f(unsigned short u) {
    unsigned v = ((unsigned)u) << 16;
    return __builtin_bit_cast(float, v);
}
static __device__ __forceinline__ unsigned short f2bf(float f) {
    unsigned u = __builtin_bit_cast(unsigned, f);
    u += 0x7fffu + ((u >> 16) & 1u);
    return (unsigned short)(u >> 16);
}

// ws layout:
//   h packed (u32, FRAGMENT-ORDERED): [2][B*H] u32
//     off(rg,c,q,m,j) = (((rg*32 + c)*4 + q)*16 + m)*8 + j
//       rg=row>>4 (0..3), m=row&15, c=k>>5 (0..31), q=(k>>3)&3, j=k&7
//     -> a wave's per-s fragment (fixed rg,c) is 512 consecutive u32 (2KB),
//        lane-major (lane = q*16+m), 8 u32 per lane: coalesced coherent loads.
constexpr size_t WOFF_HPK = 0;                             // u32 area, 2*BH u32 (= 4*BH ushort)
constexpr size_t WOFF_WHI = 4u * B_ * H_;                  // [4][1024][1024] W hi (ushort)
constexpr size_t WOFF_WLO = WOFF_WHI + 4u * 1024 * 1024;   // [4][1024][1024] W lo (ushort)
constexpr size_t WOFF_SYNC = WOFF_WLO + 4u * 1024 * 1024;  // u32 sync area (1024 u32)
// sync u32 indices: per-row-group counter rg at [rg*32] (128B padded)

// stage fp32 weights as bf16 hi/lo pairs (gate order: Wmu, Wgmu, Wga, Wa)
__global__ __launch_bounds__(256)
void conv_w_kernel(const float* __restrict__ Wmu, const float* __restrict__ Wgmu,
                   const float* __restrict__ Wga, const float* __restrict__ Wa,
                   unsigned short* __restrict__ ws)
{
    const float* src[4] = { Wmu, Wgmu, Wga, Wa };
    unsigned idx = blockIdx.x * 256 + threadIdx.x;   // [0, 4M)
    unsigned g = idx >> 20, rem = idx & 0xFFFFFu;
    float v = src[g][rem];
    unsigned short hi = f2bf(v);
    unsigned short lo = f2bf(v - bf2f(hi));
    ws[WOFF_WHI + idx] = hi;
    ws[WOFF_WLO + idx] = lo;
}

__global__ __launch_bounds__(256)
void init_h_kernel(unsigned short* __restrict__ ws)
{
    unsigned gid = blockIdx.x * 256 + threadIdx.x;   // 256 blocks -> 65536 threads
    unsigned* hpk = (unsigned*)(ws + WOFF_HPK);
    hpk[gid] = 0u;
    hpk[gid + (unsigned)BH] = 0u;
    unsigned* syncp = (unsigned*)(ws + WOFF_SYNC);
    if (gid < 1024u) syncp[gid] = 0u;
}

__global__ __launch_bounds__(256)
void sentinel_kernel(float* __restrict__ out, float val, int n)
{
    int gid = blockIdx.x * 256 + threadIdx.x;
    if (gid < n) out[gid] = val;
}

// Persistent kernel: all T steps in one launch.
// Grid: 256 blocks = 64 col-groups x 4 row-groups; 256 threads = 4 waves (K split 256).
// Weights pinned in registers. h exchanged via agent-scope relaxed atomics on a
// FRAGMENT-ORDERED packed-u32 buffer (coalesced u64 loads). Per-row-group barrier
// (the 4 row-groups are independent recurrences). x loads software-pipelined.
__global__ __launch_bounds__(256, 1)
void plasdyn_persist(const float* __restrict__ xv,
                     const float* __restrict__ Bmu, const float* __restrict__ Bgmu,
                     const float* __restrict__ Bga, const float* __restrict__ Ba,
                     float* __restrict__ out, unsigned short* __restrict__ ws)
{
    __shared__ float red[4 * 4 * 16 * RPITCH];   // [wave][gate][row][RPITCH]

    const int tid = threadIdx.x, bid = blockIdx.x;
    const int colbase = (bid & 63) * 16;
    const int rg = bid >> 6;                 // row-group 0..3
    const int rowbase = rg * 16;
    const int wave = tid >> 6, lane = tid & 63;
    const int m = lane & 15, quad = lane >> 4;
    const int kbase = wave * 256;
    const int rowm = rowbase + m;

    unsigned* hpk = (unsigned*)(ws + WOFF_HPK);      // [2][BH] packed h, fragment order
    unsigned* syncp = (unsigned*)(ws + WOFF_SYNC);

    // ---- one-time: stage this wave's weight B-fragments in registers ----
    v8s wh[4][8], wl[4][8];
    #pragma unroll
    for (int g = 0; g < 4; ++g) {
        const unsigned short* ph = ws + WOFF_WHI + ((size_t)(g * 1024 + colbase + m) << 10) + kbase;
        const unsigned short* pl = ws + WOFF_WLO + ((size_t)(g * 1024 + colbase + m) << 10) + kbase;
        #pragma unroll
        for (int s = 0; s < 8; ++s) {
            wh[g][s] = *(const v8s*)(ph + s * 32 + quad * 8);
            wl[g][s] = *(const v8s*)(pl + s * 32 + quad * 8);
        }
    }

    // combine-phase coords + hoisted biases (loop-invariant)
    const int row = tid >> 4, col = tid & 15;
    const int gcol = colbase + col;
    const int grow = rowbase + row;
    const float bmu = Bmu[gcol], bgmu = Bgmu[gcol], bga = Bga[gcol], ba = Ba[gcol];
    // write-side fragment-order offset for (grow, gcol):
    const int w_off = (((rg * 32 + (gcol >> 5)) * 4 + ((gcol >> 3) & 3)) * 16 + row) * 8 + (gcol & 7);

    // read-side: per (wave,s) fragment base in u64 units (layout guarantees evenness)
    //   base_u32(s) = (rg*32 + wave*8 + s)*512 + lane*8
    const int fragbase_u32 = (rg * 32 + wave * 8) * 512 + lane * 8;

    // ---- x prefetch pipeline: xf holds x fragments for step t (float4 pairs) ----
    float4 xf[16];
    {
        const float* xr0 = xv + ((size_t)rowm * T_ + 0) * H_;
        #pragma unroll
        for (int s = 0; s < 8; ++s) {
            const int k0 = kbase + s * 32 + quad * 8;
            xf[2 * s]     = *(const float4*)(xr0 + k0);
            xf[2 * s + 1] = *(const float4*)(xr0 + k0 + 4);
        }
    }

    for (int t = 0; t < T_; ++t) {
        const int cur = t & 1, nxt = cur ^ 1;
        const unsigned long long* h64 =
            (const unsigned long long*)(hpk + cur * BH);
        const int tn = (t + 1 < T_) ? (t + 1) : t;
        const float* xrn = xv + ((size_t)rowm * T_ + tn) * H_;

        v4f acc0 = {0,0,0,0}, acc1 = {0,0,0,0}, acc2 = {0,0,0,0}, acc3 = {0,0,0,0};

        #pragma unroll
        for (int s = 0; s < 8; ++s) {
            const int k0 = kbase + s * 32 + quad * 8;

            // h: coherent coalesced u64 loads (fragment-ordered buffer)
            const int b64 = (fragbase_u32 + s * 512) >> 1;
            unsigned long long hq0 = __hip_atomic_load(h64 + b64 + 0, __ATOMIC_RELAXED, __HIP_MEMORY_SCOPE_AGENT);
            unsigned long long hq1 = __hip_atomic_load(h64 + b64 + 1, __ATOMIC_RELAXED, __HIP_MEMORY_SCOPE_AGENT);
            unsigned long long hq2 = __hip_atomic_load(h64 + b64 + 2, __ATOMIC_RELAXED, __HIP_MEMORY_SCOPE_AGENT);
            unsigned long long hq3 = __hip_atomic_load(h64 + b64 + 3, __ATOMIC_RELAXED, __HIP_MEMORY_SCOPE_AGENT);
            unsigned hu[8];
            hu[0] = (unsigned)hq0; hu[1] = (unsigned)(hq0 >> 32);
            hu[2] = (unsigned)hq1; hu[3] = (unsigned)(hq1 >> 32);
            hu[4] = (unsigned)hq2; hu[5] = (unsigned)(hq2 >> 32);
            hu[6] = (unsigned)hq3; hu[7] = (unsigned)(hq3 >> 32);
            v8s ahi, alo;
            #pragma unroll
            for (int j = 0; j < 8; ++j) {
                ahi[j] = (short)(hu[j] >> 16);
                alo[j] = (short)(hu[j] & 0xFFFFu);
            }

            // x: fp32 -> bf16 hi/lo from prefetched regs (identical math)
            float4 f0 = xf[2 * s];
            float4 f1 = xf[2 * s + 1];
            float fv[8] = { f0.x, f0.y, f0.z, f0.w, f1.x, f1.y, f1.z, f1.w };
            v8s xh, xl;
            #pragma unroll
            for (int j = 0; j < 8; ++j) {
                unsigned short hb = f2bf(fv[j]);
                xh[j] = (short)hb;
                xl[j] = (short)f2bf(fv[j] - bf2f(hb));
            }

            acc0 = __builtin_amdgcn_mfma_f32_16x16x32_bf16(ahi, wh[0][s], acc0, 0, 0, 0);
            acc1 = __builtin_amdgcn_mfma_f32_16x16x32_bf16(ahi, wh[1][s], acc1, 0, 0, 0);
            acc2 = __builtin_amdgcn_mfma_f32_16x16x32_bf16(ahi, wh[2][s], acc2, 0, 0, 0);
            acc3 = __builtin_amdgcn_mfma_f32_16x16x32_bf16(xh,  wh[3][s], acc3, 0, 0, 0);
            acc0 = __builtin_amdgcn_mfma_f32_16x16x32_bf16(alo, wh[0][s], acc0, 0, 0, 0);
            acc1 = __builtin_amdgcn_mfma_f32_16x16x32_bf16(alo, wh[1][s], acc1, 0, 0, 0);
            acc2 = __builtin_amdgcn_mfma_f32_16x16x32_bf16(alo, wh[2][s], acc2, 0, 0, 0);
            acc3 = __builtin_amdgcn_mfma_f32_16x16x32_bf16(xl,  wh[3][s], acc3, 0, 0, 0);
            acc0 = __builtin_amdgcn_mfma_f32_16x16x32_bf16(ahi, wl[0][s], acc0, 0, 0, 0);
            acc1 = __builtin_amdgcn_mfma_f32_16x16x32_bf16(ahi, wl[1][s], acc1, 0, 0, 0);
            acc2 = __builtin_amdgcn_mfma_f32_16x16x32_bf16(ahi, wl[2][s], acc2, 0, 0, 0);
            acc3 = __builtin_amdgcn_mfma_f32_16x16x32_bf16(xh,  wl[3][s], acc3, 0, 0, 0);

            // prefetch x for step t+1 into the regs just consumed (WAR handled by compiler)
            xf[2 * s]     = *(const float4*)(xrn + k0);
            xf[2 * s + 1] = *(const float4*)(xrn + k0 + 4);
        }

        // partials -> LDS  (C/D layout: col=lane&15, row=quad*4+reg)
        {
            float* rw = red + wave * (4 * 16 * RPITCH);
            #pragma unroll
            for (int r = 0; r < 4; ++r) {
                int rr = quad * 4 + r;
                rw[(0 * 16 + rr) * RPITCH + m] = acc0[r];
                rw[(1 * 16 + rr) * RPITCH + m] = acc1[r];
                rw[(2 * 16 + rr) * RPITCH + m] = acc2[r];
                rw[(3 * 16 + rr) * RPITCH + m] = acc3[r];
            }
        }
        __syncthreads();

        // combine: one thread per (row,col) of the 16x16 tile
        {
            float z0 = 0.f, z1 = 0.f, z2 = 0.f, z3 = 0.f;
            #pragma unroll
            for (int w = 0; w < 4; ++w) {
                const float* rr = red + w * (4 * 16 * RPITCH);
                z0 += rr[(0 * 16 + row) * RPITCH + col];
                z1 += rr[(1 * 16 + row) * RPITCH + col];
                z2 += rr[(2 * 16 + row) * RPITCH + col];
                z3 += rr[(3 * 16 + row) * RPITCH + col];
            }
            z0 += bmu; z1 += bgmu; z2 += bga; z3 += ba;
            const float s1 = 1.0f / (1.0f + __expf(-z1));
            const float s2 = 1.0f / (1.0f + __expf(-z2));
            float hval = z0 * s1 + z3 * s2;
            hval = fminf(fmaxf(hval, -64.0f), 64.0f);   // NaN-squash safety

            const unsigned short hi16 = f2bf(hval);
            const unsigned short lo16 = f2bf(hval - bf2f(hi16));
            const unsigned pk = ((unsigned)hi16 << 16) | (unsigned)lo16;
            __hip_atomic_store(hpk + nxt * BH + w_off, pk,
                               __ATOMIC_RELAXED, __HIP_MEMORY_SCOPE_AGENT);
            if (t == T_ - 1) out[(size_t)grow * H_ + gcol] = hval;   // FP32 output
        }

        // ---- per-row-group barrier (64 blocks). __syncthreads drains vmcnt(0),
        // so all coherent h stores are at the LLC before we signal. ----
        if (t != T_ - 1) {
            __syncthreads();
            if (tid == 0) {
                unsigned* cnt = &syncp[rg * 32];
                __hip_atomic_fetch_add(cnt, 1u, __ATOMIC_RELAXED, __HIP_MEMORY_SCOPE_AGENT);
                const unsigned target = 64u * (unsigned)(t + 1);
                while (__hip_atomic_load(cnt, __ATOMIC_RELAXED, __HIP_MEMORY_SCOPE_AGENT) < target) {
                    __builtin_amdgcn_s_sleep(1);
                }
            }
            __syncthreads();
        }
    }
}

extern "C" void kernel_launch(void* const* d_in, const int* in_sizes, int n_in,
                              void* d_out, int out_size, void* d_ws, size_t ws_size,
                              hipStream_t stream)
{
    float* out = (float*)d_out;
    unsigned short* ws = (unsigned short*)d_ws;

    const int SZ_X = B_ * T_ * H_;
    const int SZ_W = H_ * H_;
    const int SZ_B = H_;

    bool dict_pat = (n_in == 9 &&
        in_sizes[0] == SZ_X &&
        in_sizes[1] == SZ_W && in_sizes[3] == SZ_W && in_sizes[5] == SZ_W && in_sizes[7] == SZ_W &&
        in_sizes[2] == SZ_B && in_sizes[4] == SZ_B && in_sizes[6] == SZ_B && in_sizes[8] == SZ_B);

    if (!dict_pat) {
        hipLaunchKernelGGL(sentinel_kernel, dim3((out_size + 255) / 256), dim3(256), 0, stream,
                           out, 2000.0f, out_size);
        return;
    }

    // dict order: x, W_mu, b_mu, Wg_mu, bg_mu, W_a, b_a, Wg_a, bg_a  (all fp32)
    const float* x    = (const float*)d_in[0];
    const float* Wmu  = (const float*)d_in[1];
    const float* bmu  = (const float*)d_in[2];
    const float* Wgmu = (const float*)d_in[3];
    const float* bgmu = (const float*)d_in[4];
    const float* Wa   = (const float*)d_in[5];
    const float* ba   = (const float*)d_in[6];
    const float* Wga  = (const float*)d_in[7];
    const float* bga  = (const float*)d_in[8];

    hipLaunchKernelGGL(conv_w_kernel, dim3(16384), dim3(256), 0, stream,
                       Wmu, Wgmu, Wga, Wa, ws);
    hipLaunchKernelGGL(init_h_kernel, dim3(256), dim3(256), 0, stream, ws);

    // one persistent launch runs all T=512 steps; 256 blocks @ 1 block/CU => all co-resident
    hipLaunchKernelGGL(plasdyn_persist, dim3(256), dim3(256), 0, stream,
                       x, bmu, bgmu, bga, ba, out, ws);
}